// Round 1
// baseline (108.417 us; speedup 1.0000x reference)
//
#include <hip/hip_runtime.h>
#include <math.h>

#define N_ORB   1024
#define NTIMES  1024
#define N_FZ    24
#define N_KEZ   6
#define N_TINT  64
#define N_ALPHA 512

#define SLICE_FLOATS (N_ALPHA * N_TINT)              // 32768 floats = 128 KB
#define GT_BYTES (N_FZ * SLICE_FLOATS * 4)           // 3 MB
#define P_BYTES  (NTIMES * N_ORB * 8)                // 8 MB (float2)

typedef __attribute__((address_space(1))) const unsigned int gas_u32;
typedef __attribute__((address_space(3))) unsigned int las_u32;

// width-16 global->LDS DMA; LDS dest must be wave-uniform (lane scatter is +lane*16)
__device__ __forceinline__ void gl_lds16(const float* g, float* l) {
    __builtin_amdgcn_global_load_lds((gas_u32*)g, (las_u32*)l, 16, 0, 0);
}

// ---------------------------------------------------------------------------
// Kernel 1: fused staging.
//   blocks [0,192)        : gT[fz][s][tint] transpose of grid (kEZ slice)
//   blocks [192,1216)     : P[t][o] = float2{ x = s + dal (bit-exact encode), dMagEff }
//   block  1216           : t_list = t indices counting-sorted by f0  (grouping)
// ---------------------------------------------------------------------------
__global__ __launch_bounds__(256) void stage_inputs(
    const float* __restrict__ grid, const float* __restrict__ kEZs,
    const float* __restrict__ kEZ_val_p, const float* __restrict__ alpha,
    const float* __restrict__ dMag, const float* __restrict__ alphas,
    const float* __restrict__ fZ_vals, const float* __restrict__ fZs,
    float* __restrict__ gT, float2* __restrict__ P, int* __restrict__ t_list)
{
    __shared__ float lds[64 * 65];

    int b = blockIdx.x;
    int tid = threadIdx.x;

    if (b < 192) {
        // ---- gT[fz][s][tint] = grid[fz][kez][tint][s] ----
        float kv = kEZ_val_p[0];
        int cnt = 0;
#pragma unroll
        for (int i = 0; i < N_KEZ; ++i) cnt += (kEZs[i] <= kv) ? 1 : 0;
        int kez = cnt - 1;
        kez = kez < 0 ? 0 : (kez > N_KEZ - 1 ? N_KEZ - 1 : kez);

        int fz = b >> 3, sc = b & 7;
        int w = tid >> 6, lane = tid & 63;
        const float* gsrc = grid + ((size_t)fz * N_KEZ + kez) * N_TINT * N_ALPHA;

#pragma unroll
        for (int r = 0; r < 16; ++r) {
            int tint = w * 16 + r;
            lds[tint * 65 + lane] = gsrc[(size_t)tint * N_ALPHA + sc * 64 + lane];
        }
        __syncthreads();
#pragma unroll
        for (int r = 0; r < 16; ++r) {
            int sl = w * 16 + r;
            gT[((size_t)fz * N_ALPHA + sc * 64 + sl) * N_TINT + lane] = lds[lane * 65 + sl];
        }
    } else if (b < 192 + 1024) {
        // ---- P build: 32x32 (o,t) transpose tile, float2 output ----
        float* xa  = lds;                 // [32][33]
        float* dmv = lds + 1056;

        int u = b - 192;
        int t0 = (u & 31) << 5, o0 = (u >> 5) << 5;
        int row = tid >> 5, col = tid & 31;

        float al0 = alphas[0], al1 = alphas[N_ALPHA - 1];
        float la0 = log10f(al0);
        float inv_step = 1.0f / (log10f(alphas[1]) - la0);

#pragma unroll
        for (int r = 0; r < 4; ++r) {
            int ol = (r << 3) + row;
            size_t idx = (size_t)(o0 + ol) * NTIMES + t0 + col;
            float a = alpha[idx];
            float d = dMag[idx];
            float a_ind = (log10f(a) - la0) * inv_step;
            bool geom = (a >= al0) && (a <= al1);
            // x = s + dal, bit-exact recomposition of a_ind with the
            // dynamic_slice clamp folded in (a_ind>=511 -> s=510, dal=a_ind-511)
            float x = a_ind;
            if (a_ind >= 511.0f) x = a_ind - 1.0f;
            if (!geom) x = 0.0f;
            x = fmaxf(x, 0.0f);
            xa[ol * 33 + col]  = x;
            dmv[ol * 33 + col] = geom ? d : __builtin_inff();
        }
        __syncthreads();
#pragma unroll
        for (int r = 0; r < 4; ++r) {
            int tl = (r << 3) + row;
            float2 v;
            v.x = xa[col * 33 + tl];
            v.y = dmv[col * 33 + tl];
            P[(size_t)(t0 + tl) * N_ORB + o0 + col] = v;
        }
    } else {
        // ---- t_list: counting-sort 1024 t's by f0 (23 bins) ----
        __shared__ int h[32];
        __shared__ int ps[32];
        if (tid < 32) h[tid] = 0;
        __syncthreads();

        float lf0 = log10f(fZs[0]);
        float inv_f = 1.0f / (log10f(fZs[1]) - lf0);
        int f0r[4];
#pragma unroll
        for (int k = 0; k < 4; ++k) {
            int t = tid + (k << 8);
            float fi = (log10f(fZ_vals[t]) - lf0) * inv_f;
            int f0 = (int)floorf(fi) + 1;
            f0 = f0 < 0 ? 0 : (f0 > N_FZ - 2 ? N_FZ - 2 : f0);
            f0r[k] = f0;
            atomicAdd(&h[f0], 1);
        }
        __syncthreads();
        if (tid == 0) {
            int run = 0;
#pragma unroll
            for (int i = 0; i < N_FZ; ++i) { ps[i] = run; run += h[i]; }
        }
        __syncthreads();
#pragma unroll
        for (int k = 0; k < 4; ++k) {
            int pos = atomicAdd(&ps[f0r[k]], 1);
            t_list[pos] = tid + (k << 8);
        }
    }
}

// ---------------------------------------------------------------------------
// Kernel 2: 256 blocks x 1024 threads, 4 t's per block (grouped by f0).
// Whole f0-slice (128 KB) LDS-resident -> sort-free gather, conflict-free
// (2-way alias only). Lane = (half, tint-pair): wave processes 2 orbits/iter,
// per-tint counts are lane-local (no shuffle reduction).
// LDS: 128K slice + 16K double-buffered Ptile + 8K red = 152 KB -> 1 block/CU.
// ---------------------------------------------------------------------------
__global__ __launch_bounds__(1024) void pdet_main(
    const float* __restrict__ fZ_vals, const float* __restrict__ fZs,
    const float* __restrict__ gT, const float2* __restrict__ P,
    const int* __restrict__ t_list, float* __restrict__ out)
{
    __shared__ float  g_lds[SLICE_FLOATS];   // 128 KB
    __shared__ float2 Ptile[2][N_ORB];       // 16 KB
    __shared__ uint2  red[16][64];           // 8 KB
    __shared__ int    tsh[4];

    const int tid  = threadIdx.x;
    const int w    = tid >> 6;
    const int lane = tid & 63;
    const int hh   = lane >> 5;              // which orbit of the pair
    const int tp   = lane & 31;              // tint pair index (tints 2tp, 2tp+1)
    const int tb   = blockIdx.x << 2;

    const float lf0   = log10f(fZs[0]);
    const float inv_f = 1.0f / (log10f(fZs[1]) - lf0);

    if (tid < 4) tsh[tid] = t_list[tb + tid];

    // ---- prologue: stage slice for t0 + Ptile[0] ----
    int t0 = t_list[tb];
    float fi = (log10f(fZ_vals[t0]) - lf0) * inv_f;
    int staged = (int)floorf(fi) + 1;
    staged = staged < 0 ? 0 : (staged > N_FZ - 2 ? N_FZ - 2 : staged);
    {
        const float* src = gT + (size_t)staged * SLICE_FLOATS;
#pragma unroll
        for (int r = 0; r < 8; ++r) {
            int chunk = (r << 4) + w;                      // 0..127, wave-uniform
            gl_lds16(src + (chunk << 8) + (lane << 2), &g_lds[chunk << 8]);
        }
    }
    if (w < 8) {
        const float* src = (const float*)(P + (size_t)t0 * N_ORB);
        gl_lds16(src + (w << 8) + (lane << 2), (float*)&Ptile[0][0] + (w << 8));
    }
    __syncthreads();   // drains vmcnt -> slice + Ptile[0] ready

    unsigned Aacc = 0, Bacc = 0;             // 4x byte-packed per-tint counts
    const int obase = w << 6;                // this wave's 64 orbits

#pragma unroll
    for (int q = 0; q < 4; ++q) {
        // prefetch next t's P tile into the other buffer (overlaps compute)
        if (q < 3 && w < 8) {
            int tn = t_list[tb + q + 1];
            const float* src = (const float*)(P + (size_t)tn * N_ORB);
            gl_lds16(src + (w << 8) + (lane << 2),
                     (float*)&Ptile[(q + 1) & 1][0] + (w << 8));
        }

        const float2* Pb = Ptile[q & 1];
        int ca = 0, cb = 0;
#pragma unroll 8
        for (int j = 0; j < 32; ++j) {
            float2 pd = Pb[obase + (j << 1) + hh];         // b64, 2-addr broadcast
            int   si  = (int)pd.x;                         // s (<=510 by encode)
            float dal = pd.x - (float)si;
            int   idx = (si << 6) + (tp << 1);
            float2 r0 = *(const float2*)&g_lds[idx];       // row s
            float2 r1 = *(const float2*)&g_lds[idx + 64];  // row s+1 (ds_read2_b64)
            ca += pd.y < fmaf(dal, r1.x - r0.x, r0.x);
            cb += pd.y < fmaf(dal, r1.y - r0.y, r0.y);
        }
        Aacc |= (unsigned)ca << (q << 3);                  // ca,cb <= 32, byte-safe
        Bacc |= (unsigned)cb << (q << 3);

        __syncthreads();   // everyone done with Pb & slice; prefetch drained

        if (q < 3) {       // rare: f0 boundary inside block -> restage slice
            int tn = t_list[tb + q + 1];
            float fin = (log10f(fZ_vals[tn]) - lf0) * inv_f;
            int f0n = (int)floorf(fin) + 1;
            f0n = f0n < 0 ? 0 : (f0n > N_FZ - 2 ? N_FZ - 2 : f0n);
            if (f0n != staged) {
                const float* src = gT + (size_t)f0n * SLICE_FLOATS;
#pragma unroll
                for (int r = 0; r < 8; ++r) {
                    int chunk = (r << 4) + w;
                    gl_lds16(src + (chunk << 8) + (lane << 2), &g_lds[chunk << 8]);
                }
                staged = f0n;
                __syncthreads();
            }
        }
    }

    red[w][lane] = make_uint2(Aacc, Bacc);
    __syncthreads();

    if (tid < 256) {
        const int tq  = tid >> 6;
        const int ti  = tid & 63;
        const int tpp = ti >> 1;
        const int e   = ti & 1;
        int sum = 0;
#pragma unroll
        for (int ww = 0; ww < 16; ++ww) {
            uint2 v0 = red[ww][tpp];          // half 0
            uint2 v1 = red[ww][32 + tpp];     // half 1
            unsigned u0 = e ? v0.y : v0.x;
            unsigned u1 = e ? v1.y : v1.x;
            sum += (int)((u0 >> (tq << 3)) & 255u);
            sum += (int)((u1 >> (tq << 3)) & 255u);
        }
        out[(size_t)tsh[tq] * N_TINT + ti] = (float)sum * (1.0f / 1024.0f);
    }
}

// ---------------------------------------------------------------------------
extern "C" void kernel_launch(void* const* d_in, const int* in_sizes, int n_in,
                              void* d_out, int out_size, void* d_ws, size_t ws_size,
                              hipStream_t stream) {
    const float* alpha   = (const float*)d_in[0];
    const float* dMag    = (const float*)d_in[1];
    const float* fZ_vals = (const float*)d_in[2];
    const float* kEZ_val = (const float*)d_in[3];
    const float* grid    = (const float*)d_in[4];
    const float* fZs     = (const float*)d_in[5];
    const float* kEZs    = (const float*)d_in[6];
    const float* alphas  = (const float*)d_in[7];
    float* out = (float*)d_out;

    float*  gT     = (float*)d_ws;
    float2* P      = (float2*)((char*)d_ws + GT_BYTES);
    int*    t_list = (int*)((char*)d_ws + GT_BYTES + P_BYTES);

    stage_inputs<<<dim3(192 + 1024 + 1), 256, 0, stream>>>(
        grid, kEZs, kEZ_val, alpha, dMag, alphas, fZ_vals, fZs, gT, P, t_list);
    pdet_main<<<dim3(256), 1024, 0, stream>>>(fZ_vals, fZs, gT, P, t_list, out);
}

// Round 2
// 107.492 us; speedup vs baseline: 1.0086x; 1.0086x over previous
//
#include <hip/hip_runtime.h>
#include <math.h>

#define N_ORB   1024
#define NTIMES  1024
#define N_FZ    24
#define N_KEZ   6
#define N_TINT  64
#define N_ALPHA 512

// Workspace:
//   gT : [N_FZ][N_ALPHA][N_TINT] float  = 3,145,728 B  (grid slice, transposed)
//   P  : [NTIMES][N_ORB] float2         = 8,388,608 B  {x = s+dal (bit-exact == a_ind), dMagEff}
#define GT_BYTES (N_FZ * N_ALPHA * N_TINT * 4)

// ---------------------------------------------------------------------------
// Kernel 1: fused input staging. Blocks 0..191: gT transpose (64tint x 64s
// tile). Blocks 192..1215: P build, 32x32 (o,t) tiles.
// P encode (proven bit-exact in prior round, absmax identical):
//   x = a_ind            (si = (int)x, dal = x - si reconstruct exactly)
//   a_ind >= 511 -> x = a_ind - 1   (folds the dynamic_slice clamp: si=510,
//                                    dal = a_ind - 511; subtraction exact)
//   dead orbit -> x = 0, y = +inf
// ---------------------------------------------------------------------------
__global__ __launch_bounds__(256) void stage_inputs(
    const float* __restrict__ grid, const float* __restrict__ kEZs,
    const float* __restrict__ kEZ_val_p, const float* __restrict__ alpha,
    const float* __restrict__ dMag, const float* __restrict__ alphas,
    float* __restrict__ gT, float2* __restrict__ P)
{
    __shared__ float lds[64 * 65];      // gT branch uses all; P branch aliases

    int b = blockIdx.x;
    int tid = threadIdx.x;

    if (b < 192) {
        // ---- gT[fz][s][tint] = grid[fz][kez][tint][s] ----
        float kv = kEZ_val_p[0];
        int cnt = 0;
#pragma unroll
        for (int i = 0; i < N_KEZ; ++i) cnt += (kEZs[i] <= kv) ? 1 : 0;
        int kez = cnt - 1;
        kez = kez < 0 ? 0 : (kez > N_KEZ - 1 ? N_KEZ - 1 : kez);

        int fz = b >> 3, sc = b & 7;
        int w = tid >> 6, lane = tid & 63;
        const float* gsrc = grid + ((size_t)fz * N_KEZ + kez) * N_TINT * N_ALPHA;

#pragma unroll
        for (int r = 0; r < 16; ++r) {
            int tint = w * 16 + r;
            lds[tint * 65 + lane] = gsrc[(size_t)tint * N_ALPHA + sc * 64 + lane];
        }
        __syncthreads();
#pragma unroll
        for (int r = 0; r < 16; ++r) {
            int sl = w * 16 + r;
            gT[((size_t)fz * N_ALPHA + sc * 64 + sl) * N_TINT + lane] = lds[lane * 65 + sl];
        }
    } else {
        // ---- P[t][o] = float2{x, dMagEff}, 32x32 transpose tile ----
        float* xa  = lds;                // [32][33]
        float* dmv = lds + 1056;

        int u = b - 192;                 // 0..1023
        int t0 = (u & 31) << 5, o0 = (u >> 5) << 5;
        int row = tid >> 5, col = tid & 31;

        float al0 = alphas[0], al1 = alphas[N_ALPHA - 1];
        float la0 = log10f(al0);
        float inv_step = 1.0f / (log10f(alphas[1]) - la0);

#pragma unroll
        for (int r = 0; r < 4; ++r) {
            int ol = (r << 3) + row;
            size_t idx = (size_t)(o0 + ol) * NTIMES + t0 + col;
            float a = alpha[idx];
            float d = dMag[idx];
            float a_ind = (log10f(a) - la0) * inv_step;
            bool geom = (a >= al0) && (a <= al1);
            float x = a_ind;
            if (a_ind >= 511.0f) x = a_ind - 1.0f;
            if (!geom) x = 0.0f;
            x = fmaxf(x, 0.0f);
            xa[ol * 33 + col]  = x;
            dmv[ol * 33 + col] = geom ? d : __builtin_inff();
        }
        __syncthreads();
#pragma unroll
        for (int r = 0; r < 4; ++r) {
            int tl = (r << 3) + row;
            float2 v;
            v.x = xa[col * 33 + tl];
            v.y = dmv[col * 33 + tl];
            P[(size_t)(t0 + tl) * N_ORB + o0 + col] = v;
        }
    }
}

// ---------------------------------------------------------------------------
// Kernel 2: one block per t (proven round-0 chassis, float2 Psort).
// Phase A: counting-sort orbits by s into LDS (dead orbits -> bin 511 tail).
// Phase B: wave w owns sorted range [w*256, w*256+256), 4 ADJACENT sorted
// orbits per iteration (one per 16-lane group) -> g-loads mostly hit the
// same/adjacent rows, rows advance monotonically (L1-resident).
// LDS = 8K Psort + 2K hist + 2K histPS + 1K red ~= 13.3 KB -> 4 blocks/CU
// (grid-bound), 16 waves/CU.
// ---------------------------------------------------------------------------
__global__ __launch_bounds__(256) void pdet_main(
    const float* __restrict__ fZ_vals, const float* __restrict__ fZs,
    const float* __restrict__ gT, const float2* __restrict__ P,
    float* __restrict__ out)
{
    __shared__ float2 Psort[N_ORB];      // 8 KB
    __shared__ int    hist[512];
    __shared__ int    histPS[512];
    __shared__ int    red[4 * 64];

    int t = blockIdx.x;
    int tid = threadIdx.x;
    int w = tid >> 6, lane = tid & 63;

    float lf0 = log10f(fZs[0]);
    float inv_f = 1.0f / (log10f(fZs[1]) - lf0);
    float fi = (log10f(fZ_vals[t]) - lf0) * inv_f;
    int f0 = (int)floorf(fi) + 1;
    f0 = f0 < 0 ? 0 : (f0 > N_FZ - 2 ? N_FZ - 2 : f0);

    const float*  gB = gT + (size_t)f0 * N_ALPHA * N_TINT;
    const float2* Pt = P + (size_t)t * N_ORB;

    // ---- Phase A ----
    hist[tid] = 0; hist[tid + 256] = 0;
    __syncthreads();

    float2 v[4];
    int    bin[4];
#pragma unroll
    for (int k = 0; k < 4; ++k) {
        v[k] = Pt[tid + k * 256];
        int s = (int)v[k].x;             // si in [0,510] for live orbits
        bin[k] = isinf(v[k].y) ? 511 : s;
        atomicAdd(&hist[bin[k]], 1);
    }
    __syncthreads();

    if (tid < 64) {                      // wave 0: exclusive scan of 512 bins
        int pre[8]; int run = 0;
#pragma unroll
        for (int j = 0; j < 8; ++j) { pre[j] = run; run += hist[tid * 8 + j]; }
        int inc = run;
#pragma unroll
        for (int d = 1; d < 64; d <<= 1) {
            int n = __shfl_up(inc, d);
            if (lane >= d) inc += n;
        }
        int excl = inc - run;
#pragma unroll
        for (int j = 0; j < 8; ++j) histPS[tid * 8 + j] = excl + pre[j];
    }
    __syncthreads();

#pragma unroll
    for (int k = 0; k < 4; ++k) {
        int pos = atomicAdd(&histPS[bin[k]], 1);
        Psort[pos] = v[k];
    }
    __syncthreads();

    // ---- Phase B ----
    int q  = lane >> 4;                  // group 0..3 -> adjacent sorted orbit
    int tg = (lane & 15) << 2;           // tint quad
    int base = w * 256;                  // this wave's sorted range

    int c0 = 0, c1 = 0, c2 = 0, c3 = 0;

#pragma unroll 4
    for (int it = 0; it < 64; ++it) {
        float2 pd = Psort[base + it * 4 + q];
        float x  = pd.x;
        float dm = pd.y;
        int   si = (int)x;               // decode: s
        float dal = x - (float)si;       //         dal (exact)
        const float4* rowp = reinterpret_cast<const float4*>(gB + (si << 6) + tg);
        float4 g0 = rowp[0];
        float4 g1 = rowp[16];            // row s+1
        c0 += dm < fmaf(dal, g1.x - g0.x, g0.x);
        c1 += dm < fmaf(dal, g1.y - g0.y, g0.y);
        c2 += dm < fmaf(dal, g1.z - g0.z, g0.z);
        c3 += dm < fmaf(dal, g1.w - g0.w, g0.w);
    }

    c0 += __shfl_xor(c0, 16); c0 += __shfl_xor(c0, 32);
    c1 += __shfl_xor(c1, 16); c1 += __shfl_xor(c1, 32);
    c2 += __shfl_xor(c2, 16); c2 += __shfl_xor(c2, 32);
    c3 += __shfl_xor(c3, 16); c3 += __shfl_xor(c3, 32);

    if (lane < 16) {
        red[w * 64 + lane * 4 + 0] = c0;
        red[w * 64 + lane * 4 + 1] = c1;
        red[w * 64 + lane * 4 + 2] = c2;
        red[w * 64 + lane * 4 + 3] = c3;
    }
    __syncthreads();
    if (tid < 64) {
        int tot = red[tid] + red[64 + tid] + red[128 + tid] + red[192 + tid];
        out[(size_t)t * N_TINT + tid] = (float)tot * (1.0f / 1024.0f);
    }
}

// ---------------------------------------------------------------------------
extern "C" void kernel_launch(void* const* d_in, const int* in_sizes, int n_in,
                              void* d_out, int out_size, void* d_ws, size_t ws_size,
                              hipStream_t stream) {
    const float* alpha   = (const float*)d_in[0];
    const float* dMag    = (const float*)d_in[1];
    const float* fZ_vals = (const float*)d_in[2];
    const float* kEZ_val = (const float*)d_in[3];
    const float* grid    = (const float*)d_in[4];
    const float* fZs     = (const float*)d_in[5];
    const float* kEZs    = (const float*)d_in[6];
    const float* alphas  = (const float*)d_in[7];
    float* out = (float*)d_out;

    float*  gT = (float*)d_ws;
    float2* P  = (float2*)((char*)d_ws + GT_BYTES);

    stage_inputs<<<dim3(192 + 1024), 256, 0, stream>>>(
        grid, kEZs, kEZ_val, alpha, dMag, alphas, gT, P);
    pdet_main<<<dim3(NTIMES), 256, 0, stream>>>(fZ_vals, fZs, gT, P, out);
}